// Round 9
// baseline (735.542 us; speedup 1.0000x reference)
//
#include <hip/hip_runtime.h>

// Problem constants
#define BB   64
#define SS   512
#define DD   128
#define DFFc 256
#define HH   4
#define TT   9
#define LL   2
#define HDc  32
#define NN   (BB*SS)   // 32768 tokens

// Workspace layout (float offsets). Region time-sharing (r9):
//  OFF_X   : xA fp32 (persistent residual)
//  OFF_Y   : xB fp32; Kl/Vl bf16 during attn (dead outside)
//  OFF_QKV : qkv fp32 (until attn done) -> ffh/ffl bf16 (FF1 out, FF2 in)
//  OFF_CTX : XAh/XAl bf16 (QKV-gemm in) -> ctxh/ctxl bf16 (attn out, Wo in)
//            -> next XAh/XAl -> CRF Mbuf at the very end
//  OFF_KT  : Kh/Vh bf16 during attn -> xBh/xBl bf16 (LN1 out, FF1 in)
//  OFF_EM  : per-layer weight pack Wh|Wl (131072 floats) -> em (k_emis, end)
#define OFF_X    0
#define OFF_Y    (NN*DD)
#define OFF_QKV  (2*NN*DD)
#define OFF_CTX  (5*NN*DD)
#define OFF_KT   (6*NN*DD)
#define OFF_EM   (7*NN*DD)
#define OFF_PART (7*NN*DD + NN*TT)

typedef __attribute__((ext_vector_type(8))) short short8;
typedef __attribute__((ext_vector_type(8))) unsigned short ushort8;
typedef __attribute__((ext_vector_type(4))) float f32x4;

__device__ __forceinline__ unsigned short f2bf(float f) {
  unsigned int u = __float_as_uint(f);
  u += 0x7FFFu + ((u >> 16) & 1u);           // RNE; inputs are finite
  return (unsigned short)(u >> 16);
}
__device__ __forceinline__ float bf2f(unsigned short h) {
  return __uint_as_float(((unsigned int)h) << 16);
}

// ---------------------------------------------------------------------------
// Embedding + positional encoding; emits fp32 AND bf16 hi/lo pack.
__global__ void k_embed(const int* __restrict__ sent, const float* __restrict__ emb,
                        float* __restrict__ x,
                        unsigned short* __restrict__ xh, unsigned short* __restrict__ xl) {
  int n = blockIdx.x;
  int d = threadIdx.x;
  int tok = sent[n];
  int s = n & (SS - 1);
  float e = (tok != 0) ? emb[(size_t)tok * DD + d] : 0.f;
  int i = d >> 1;
  float dv = expf((float)(2 * i) * (-9.210340371976184f / (float)DD));
  float ang = (float)s * dv;
  float pe = (d & 1) ? cosf(ang) : sinf(ang);
  float v = e + pe;
  size_t o = (size_t)n * DD + d;
  x[o] = v;
  unsigned short h = f2bf(v);
  xh[o] = h;
  xl[o] = f2bf(v - bf2f(h));
}

// ---------------------------------------------------------------------------
// Pack one layer's weights to bf16 hi/lo into the em region.
// Layout (ushort offsets): Wqkv[0,49152) Wo[49152,65536) W1[65536,98304) W2[98304,131072)
__global__ void k_packw(const float* __restrict__ Wqkv, const float* __restrict__ Wo,
                        const float* __restrict__ W1, const float* __restrict__ W2,
                        unsigned short* __restrict__ Wh, unsigned short* __restrict__ Wl) {
  int idx = (blockIdx.x * 256 + threadIdx.x) * 4;   // 131072 floats total
  const float* src;
  int off;
  if (idx < 49152)      { src = Wqkv; off = idx; }
  else if (idx < 65536) { src = Wo;   off = idx - 49152; }
  else if (idx < 98304) { src = W1;   off = idx - 65536; }
  else                  { src = W2;   off = idx - 98304; }
  float4 v = *(const float4*)(src + off);
  unsigned short h0 = f2bf(v.x), h1 = f2bf(v.y), h2 = f2bf(v.z), h3 = f2bf(v.w);
  Wh[idx + 0] = h0; Wh[idx + 1] = h1; Wh[idx + 2] = h2; Wh[idx + 3] = h3;
  Wl[idx + 0] = f2bf(v.x - bf2f(h0));
  Wl[idx + 1] = f2bf(v.y - bf2f(h1));
  Wl[idx + 2] = f2bf(v.z - bf2f(h2));
  Wl[idx + 3] = f2bf(v.w - bf2f(h3));
}

// ---------------------------------------------------------------------------
// MFMA GEMM (split-bf16 3-term): Y[n][c] = act(Xrow . Wrow + bias).
// Block 256 thr / 4 waves; wave = 16 rows x 64 cols; no LDS (direct 16B loads).
// Grid 1-D: id % ncb = col-block (consecutive blocks share X rows in L2).
template <int KTOT, bool RELU, bool PACKOUT>
__global__ __launch_bounds__(256) void k_bgemm(
    const unsigned short* __restrict__ Xh, const unsigned short* __restrict__ Xl,
    const unsigned short* __restrict__ Wh, const unsigned short* __restrict__ Wl,
    const float* __restrict__ bias, float* __restrict__ Y, int ldY,
    unsigned short* __restrict__ Yh, unsigned short* __restrict__ Yl,
    int ncb) {
  const int id = blockIdx.x;
  const int cb = id % ncb, rb = id / ncb;
  const int tid = threadIdx.x, w = tid >> 6, lane = tid & 63;
  const int l15 = lane & 15, kg = lane >> 4;
  const int n0 = rb * 64 + w * 16;
  const int c0 = cb * 64;
  f32x4 acc[4] = {};
  const unsigned short* xph = Xh + (size_t)(n0 + l15) * KTOT + kg * 8;
  const unsigned short* xpl = Xl + (size_t)(n0 + l15) * KTOT + kg * 8;
  #pragma unroll
  for (int ks = 0; ks < KTOT / 32; ks++) {
    short8 ah = *(const short8*)(xph + ks * 32);
    short8 al = *(const short8*)(xpl + ks * 32);
    #pragma unroll
    for (int ct = 0; ct < 4; ct++) {
      size_t wo = (size_t)(c0 + ct * 16 + l15) * KTOT + ks * 32 + kg * 8;
      short8 bh = *(const short8*)(Wh + wo);
      short8 bl = *(const short8*)(Wl + wo);
      acc[ct] = __builtin_amdgcn_mfma_f32_16x16x32_bf16(ah, bh, acc[ct], 0, 0, 0);
      acc[ct] = __builtin_amdgcn_mfma_f32_16x16x32_bf16(ah, bl, acc[ct], 0, 0, 0);
      acc[ct] = __builtin_amdgcn_mfma_f32_16x16x32_bf16(al, bh, acc[ct], 0, 0, 0);
    }
  }
  // D layout: row = kg*4+j -> n, col = l15 -> c (verified via attn kernel)
  #pragma unroll
  for (int ct = 0; ct < 4; ct++) {
    int c = c0 + ct * 16 + l15;
    float bi = bias[c];
    #pragma unroll
    for (int j = 0; j < 4; j++) {
      float v = acc[ct][j] + bi;
      if (RELU) v = fmaxf(v, 0.f);
      int n = n0 + kg * 4 + j;
      if (PACKOUT) {
        unsigned short h = f2bf(v);
        Yh[(size_t)n * ldY + c] = h;
        Yl[(size_t)n * ldY + c] = f2bf(v - bf2f(h));
      } else {
        Y[(size_t)n * ldY + c] = v;
      }
    }
  }
}

// ---------------------------------------------------------------------------
// MFMA GEMM + bias + residual + LayerNorm (full 128-col rows per block).
// Wave = 16 rows x 128 cols (8 col-tiles). Row stats via 16-lane shfl reduce.
template <int KTOT>
__global__ __launch_bounds__(256) void k_bgemm_ln(
    const unsigned short* __restrict__ Xh, const unsigned short* __restrict__ Xl,
    const unsigned short* __restrict__ Wh, const unsigned short* __restrict__ Wl,
    const float* __restrict__ bias, const float* __restrict__ Res,
    const float* __restrict__ gam, const float* __restrict__ bet,
    float* __restrict__ Y,
    unsigned short* __restrict__ Yh, unsigned short* __restrict__ Yl,
    int dopack) {
  const int tid = threadIdx.x, w = tid >> 6, lane = tid & 63;
  const int l15 = lane & 15, kg = lane >> 4;
  const int n0 = blockIdx.x * 64 + w * 16;
  f32x4 acc[8] = {};
  const unsigned short* xph = Xh + (size_t)(n0 + l15) * KTOT + kg * 8;
  const unsigned short* xpl = Xl + (size_t)(n0 + l15) * KTOT + kg * 8;
  #pragma unroll
  for (int ks = 0; ks < KTOT / 32; ks++) {
    short8 ah = *(const short8*)(xph + ks * 32);
    short8 al = *(const short8*)(xpl + ks * 32);
    #pragma unroll
    for (int ct = 0; ct < 8; ct++) {
      size_t wo = (size_t)(ct * 16 + l15) * KTOT + ks * 32 + kg * 8;
      short8 bh = *(const short8*)(Wh + wo);
      short8 bl = *(const short8*)(Wl + wo);
      acc[ct] = __builtin_amdgcn_mfma_f32_16x16x32_bf16(ah, bh, acc[ct], 0, 0, 0);
      acc[ct] = __builtin_amdgcn_mfma_f32_16x16x32_bf16(ah, bl, acc[ct], 0, 0, 0);
      acc[ct] = __builtin_amdgcn_mfma_f32_16x16x32_bf16(al, bh, acc[ct], 0, 0, 0);
    }
  }
  #pragma unroll
  for (int j = 0; j < 4; j++) {
    int n = n0 + kg * 4 + j;
    float v[8], s1 = 0.f, s2 = 0.f;
    #pragma unroll
    for (int ct = 0; ct < 8; ct++) {
      int c = ct * 16 + l15;
      float t = acc[ct][j] + bias[c] + Res[(size_t)n * DD + c];
      v[ct] = t;
      s1 += t;
      s2 += t * t;
    }
    #pragma unroll
    for (int off = 1; off <= 8; off <<= 1) {
      s1 += __shfl_xor(s1, off);
      s2 += __shfl_xor(s2, off);
    }
    float mu = s1 * 0.0078125f;
    float var = s2 * 0.0078125f - mu * mu;
    float rstd = rsqrtf(var + 1e-5f);
    #pragma unroll
    for (int ct = 0; ct < 8; ct++) {
      int c = ct * 16 + l15;
      float o = (v[ct] - mu) * rstd * gam[c] + bet[c];
      size_t oo = (size_t)n * DD + c;
      Y[oo] = o;
      if (dopack) {
        unsigned short h = f2bf(o);
        Yh[oo] = h;
        Yl[oo] = f2bf(o - bf2f(h));
      }
    }
  }
}

// ---------------------------------------------------------------------------
// Pack K and V of qkv into split-bf16 (hi+lo): Kh/Kl [bh][s][32], Vh/Vl [bh][32][s].
__global__ void k_pack(const float* __restrict__ qkv,
                       unsigned short* __restrict__ Kh, unsigned short* __restrict__ Kl,
                       unsigned short* __restrict__ Vh, unsigned short* __restrict__ Vl) {
  const int st = blockIdx.x * 64;
  const int bh = blockIdx.y;
  const int b = bh >> 2, h = bh & 3;
  const int tid = threadIdx.x;
  __shared__ float tile[64][33];
  #pragma unroll
  for (int p = 0; p < 8; p++) {
    int sl = p * 8 + (tid >> 5);
    int d = tid & 31;
    const float* src = qkv + (size_t)(b * SS + st + sl) * 384 + h * 32 + d;
    float kv = src[128];
    unsigned short khu = f2bf(kv);
    size_t o = (size_t)(bh * SS + st + sl) * 32 + d;
    Kh[o] = khu;
    Kl[o] = f2bf(kv - bf2f(khu));
    tile[sl][d] = src[256];              // V slice to LDS for transpose
  }
  __syncthreads();
  int d = tid >> 3, s0 = (tid & 7) * 8;
  ushort8 vh, vl;
  #pragma unroll
  for (int i = 0; i < 8; i++) {
    float v = tile[s0 + i][d];
    unsigned short hu = f2bf(v);
    vh[i] = hu;
    vl[i] = f2bf(v - bf2f(hu));
  }
  size_t o = (size_t)(bh * 32 + d) * SS + st + s0;
  *(ushort8*)&Vh[o] = vh;
  *(ushort8*)&Vl[o] = vl;
}

// ---------------------------------------------------------------------------
// MFMA attention (split-bf16, 3-term). Epilogue now writes ctx as bf16 hi/lo
// pack only (sole consumer is the Wo MFMA-GEMM).
__global__ __launch_bounds__(256) void k_attn(const float* __restrict__ qkv,
    const unsigned short* __restrict__ Kh, const unsigned short* __restrict__ Kl,
    const unsigned short* __restrict__ Vh, const unsigned short* __restrict__ Vl,
    const int* __restrict__ sent,
    unsigned short* __restrict__ ctxh, unsigned short* __restrict__ ctxl) {
  const int id = blockIdx.x;
  const int xcd = id & 7, rem = id >> 3;
  const int qt = rem & 7;                 // 0..7
  const int bh = xcd + 8 * (rem >> 3);    // 0..255
  const int b = bh >> 2, h = bh & 3;
  const int tid = threadIdx.x, w = tid >> 6, lane = tid & 63;
  const int l15 = lane & 15, kg = lane >> 4;

  __shared__ float kb_lds[512];
  __shared__ unsigned short Ph[4][16][136];   // [wave][q][ks(128)+pad]
  __shared__ unsigned short Pl[4][16][136];
  __shared__ float l_lds[4][16];

  for (int i = tid; i < 512; i += 256)
    kb_lds[i] = (sent[b * SS + i] != 0) ? 0.f : -1e9f;
  __syncthreads();

  const int qrow = qt * 64 + w * 16 + l15;
  const float* qp = qkv + (size_t)(b * SS + qrow) * 384 + h * 32 + kg * 8;
  short8 qh, ql;
  #pragma unroll
  for (int i = 0; i < 8; i++) {
    float v = qp[i];
    unsigned short hu = f2bf(v);
    qh[i] = (short)hu;
    ql[i] = (short)f2bf(v - bf2f(hu));
  }

  f32x4 acc0 = {0.f, 0.f, 0.f, 0.f};
  f32x4 acc1 = {0.f, 0.f, 0.f, 0.f};
  float ls[4] = {0.f, 0.f, 0.f, 0.f};
  const float scale = 0.17677669529663687f; // 1/sqrt(32)

  const unsigned short* KhB = Kh + (size_t)bh * SS * 32;
  const unsigned short* KlB = Kl + (size_t)bh * SS * 32;
  const unsigned short* VhB = Vh + (size_t)bh * 32 * SS;
  const unsigned short* VlB = Vl + (size_t)bh * 32 * SS;

  for (int c = 0; c < 4; c++) {
    const int ksb = c * 128;
    f32x4 sc[8];
    #pragma unroll
    for (int t = 0; t < 8; t++) {
      size_t ko = (size_t)(ksb + t * 16 + l15) * 32 + kg * 8;
      short8 kh_ = *(const short8*)(KhB + ko);
      short8 kl_ = *(const short8*)(KlB + ko);
      f32x4 z = {0.f, 0.f, 0.f, 0.f};
      f32x4 s = __builtin_amdgcn_mfma_f32_16x16x32_bf16(qh, kh_, z, 0, 0, 0);
      s = __builtin_amdgcn_mfma_f32_16x16x32_bf16(qh, kl_, s, 0, 0, 0);
      s = __builtin_amdgcn_mfma_f32_16x16x32_bf16(ql, kh_, s, 0, 0, 0);
      sc[t] = s;
    }
    #pragma unroll
    for (int t = 0; t < 8; t++) {
      float kbv = kb_lds[ksb + t * 16 + l15];
      #pragma unroll
      for (int j = 0; j < 4; j++) {
        float s = fmaf(sc[t][j], scale, kbv);
        float p = __expf(s);
        ls[j] += p;
        unsigned short ph = f2bf(p);
        Ph[w][kg * 4 + j][t * 16 + l15] = ph;
        Pl[w][kg * 4 + j][t * 16 + l15] = f2bf(p - bf2f(ph));
      }
    }
    #pragma unroll
    for (int k4 = 0; k4 < 4; k4++) {
      short8 ph_ = *(const short8*)&Ph[w][l15][k4 * 32 + kg * 8];
      short8 pl_ = *(const short8*)&Pl[w][l15][k4 * 32 + kg * 8];
      size_t vo0 = (size_t)l15 * SS + ksb + k4 * 32 + kg * 8;
      size_t vo1 = (size_t)(16 + l15) * SS + ksb + k4 * 32 + kg * 8;
      short8 vh0 = *(const short8*)(VhB + vo0);
      short8 vl0 = *(const short8*)(VlB + vo0);
      acc0 = __builtin_amdgcn_mfma_f32_16x16x32_bf16(vh0, ph_, acc0, 0, 0, 0);
      acc0 = __builtin_amdgcn_mfma_f32_16x16x32_bf16(vh0, pl_, acc0, 0, 0, 0);
      acc0 = __builtin_amdgcn_mfma_f32_16x16x32_bf16(vl0, ph_, acc0, 0, 0, 0);
      short8 vh1 = *(const short8*)(VhB + vo1);
      short8 vl1 = *(const short8*)(VlB + vo1);
      acc1 = __builtin_amdgcn_mfma_f32_16x16x32_bf16(vh1, ph_, acc1, 0, 0, 0);
      acc1 = __builtin_amdgcn_mfma_f32_16x16x32_bf16(vh1, pl_, acc1, 0, 0, 0);
      acc1 = __builtin_amdgcn_mfma_f32_16x16x32_bf16(vl1, ph_, acc1, 0, 0, 0);
    }
  }
  #pragma unroll
  for (int j = 0; j < 4; j++) {
    #pragma unroll
    for (int off = 1; off <= 8; off <<= 1) ls[j] += __shfl_xor(ls[j], off);
  }
  if (l15 == 0) {
    #pragma unroll
    for (int j = 0; j < 4; j++) l_lds[w][kg * 4 + j] = ls[j];
  }
  float linv = 1.f / l_lds[w][l15];
  size_t co = (size_t)(b * SS + qrow) * DD + h * 32;
  #pragma unroll
  for (int j = 0; j < 4; j++) {
    float v0 = acc0[j] * linv;
    float v1 = acc1[j] * linv;
    unsigned short h0 = f2bf(v0), h1 = f2bf(v1);
    ctxh[co + kg * 4 + j] = h0;
    ctxl[co + kg * 4 + j] = f2bf(v0 - bf2f(h0));
    ctxh[co + 16 + kg * 4 + j] = h1;
    ctxl[co + 16 + kg * 4 + j] = f2bf(v1 - bf2f(h1));
  }
}

// ---------------------------------------------------------------------------
__global__ void k_emis(const float* __restrict__ X, const float* __restrict__ Wtag,
                       const float* __restrict__ btag, float* __restrict__ em) {
  int idx = blockIdx.x * 256 + threadIdx.x;
  if (idx >= NN * TT) return;
  int n = idx / TT, t = idx - n * TT;
  const float* xr = X + (size_t)n * DD;
  const float* wr = Wtag + (size_t)t * DD;
  float acc = 0.f;
  #pragma unroll
  for (int k = 0; k < DD / 4; k++) {
    float4 x4 = *(const float4*)(xr + 4 * k);
    float4 w4 = *(const float4*)(wr + 4 * k);
    acc += x4.x * w4.x + x4.y * w4.y + x4.z * w4.z + x4.w * w4.w;
  }
  em[idx] = acc + btag[t];
}

// ---------------------------------------------------------------------------
// CRF log-semiring matrix scan (r8, verified).
__global__ void k_crf_scan(const float* __restrict__ em, const int* __restrict__ sent,
                           const float* __restrict__ trans, float* __restrict__ M) {
  const int i = blockIdx.x;     // row 0..8
  const int c = blockIdx.y;     // chunk 0..7
  const int b = blockIdx.z;     // batch
  const int lane = threadIdx.x; // 64
  const int j = (lane < TT) ? lane : 0;
  float tr[TT];
  #pragma unroll
  for (int k = 0; k < TT; k++) tr[k] = trans[k * TT + j];
  const float* emb_ = em + (size_t)b * SS * TT;
  float v = (j == i) ? 0.f : -1e30f;
  const int s0 = 1 + c * 64;
  const int s1 = (s0 + 64 < SS) ? s0 + 64 : SS;
  for (int s = s0; s < s1; s++) {
    int tok = sent[b * SS + s];
    if (tok != 0) {
      float a[TT];
      #pragma unroll
      for (int k = 0; k < TT; k++) a[k] = __shfl(v, k) + tr[k];
      float m = a[0];
      #pragma unroll
      for (int k = 1; k < TT; k++) m = fmaxf(m, a[k]);
      float sum = 0.f;
      #pragma unroll
      for (int k = 0; k < TT; k++) sum += __expf(a[k] - m);
      v = emb_[s * TT + j] + m + __logf(sum);
    }
  }
  if (lane < TT) M[(((size_t)b * 8 + c) * TT + i) * TT + j] = v;
}

__global__ void k_crf_comb(const float* __restrict__ em, const int* __restrict__ sent,
                           const int* __restrict__ tags, const float* __restrict__ trans,
                           const float* __restrict__ start_t, const float* __restrict__ end_t,
                           const float* __restrict__ M, float* __restrict__ part) {
  const int b = blockIdx.x;
  const int lane = threadIdx.x;
  const int j = (lane < TT) ? lane : 0;
  const float* emb_ = em + (size_t)b * SS * TT;
  float fv = start_t[j] + emb_[j];
  #pragma unroll
  for (int c = 0; c < 8; c++) {
    const float* Mc = M + (((size_t)b * 8 + c) * TT) * TT;
    float a[TT];
    #pragma unroll
    for (int k = 0; k < TT; k++) a[k] = __shfl(fv, k) + Mc[k * TT + j];
    float m = a[0];
    #pragma unroll
    for (int k = 1; k < TT; k++) m = fmaxf(m, a[k]);
    float sum = 0.f;
    #pragma unroll
    for (int k = 0; k < TT; k++) sum += __expf(a[k] - m);
    fv = m + __logf(sum);
  }
  float aa[TT];
  #pragma unroll
  for (int i = 0; i < TT; i++) aa[i] = __shfl(fv, i) + end_t[i];
  float m2 = aa[0];
  #pragma unroll
  for (int i = 1; i < TT; i++) m2 = fmaxf(m2, aa[i]);
  float sum2 = 0.f;
  #pragma unroll
  for (int i = 0; i < TT; i++) sum2 += __expf(aa[i] - m2);
  float fwd = m2 + __logf(sum2);
  float p = 0.f;
  int cnt = 0;
  #pragma unroll
  for (int ii = 0; ii < 8; ii++) {
    int s = lane + 64 * ii;
    cnt += (sent[b * SS + s] != 0) ? 1 : 0;
    int s2 = s + 1;
    if (s2 < SS && sent[b * SS + s2] != 0) {
      int tp = tags[b * SS + s2 - 1];
      int tc = tags[b * SS + s2];
      p += trans[tp * TT + tc] + emb_[(size_t)s2 * TT + tc];
    }
  }
  #pragma unroll
  for (int off = 32; off >= 1; off >>= 1) {
    p += __shfl_xor(p, off);
    cnt += __shfl_xor(cnt, off);
  }
  if (lane == 0) {
    int t0 = tags[b * SS];
    float score = start_t[t0] + emb_[t0] + p;
    int lastt = tags[b * SS + cnt - 1];
    score += end_t[lastt];
    part[b] = fwd - score;
  }
}

__global__ void k_final(const float* __restrict__ part, float* __restrict__ out) {
  float v = part[threadIdx.x];
  #pragma unroll
  for (int off = 32; off >= 1; off >>= 1) v += __shfl_xor(v, off);
  if (threadIdx.x == 0) out[0] = v * (1.f / 64.f);
}

// ---------------------------------------------------------------------------
extern "C" void kernel_launch(void* const* d_in, const int* in_sizes, int n_in,
                              void* d_out, int out_size, void* d_ws, size_t ws_size,
                              hipStream_t stream) {
  const int*   sent  = (const int*)d_in[0];
  const int*   tags  = (const int*)d_in[1];
  const float* emb   = (const float*)d_in[2];
  const float* Wqkv  = (const float*)d_in[3];
  const float* bqkv  = (const float*)d_in[4];
  const float* Wo    = (const float*)d_in[5];
  const float* bo    = (const float*)d_in[6];
  const float* W1    = (const float*)d_in[7];
  const float* b1f   = (const float*)d_in[8];
  const float* W2    = (const float*)d_in[9];
  const float* b2f   = (const float*)d_in[10];
  const float* ln1g  = (const float*)d_in[11];
  const float* ln1b  = (const float*)d_in[12];
  const float* ln2g  = (const float*)d_in[13];
  const float* ln2b  = (const float*)d_in[14];
  const float* Wtag  = (const float*)d_in[15];
  const float* btag  = (const float*)d_in[16];
  const float* trans = (const float*)d_in[17];
  const float* st    = (const float*)d_in[18];
  const float* et    = (const float*)d_in[19];

  float* ws   = (float*)d_ws;
  float* xA   = ws + OFF_X;
  float* xB   = ws + OFF_Y;
  float* qkv  = ws + OFF_QKV;
  float* em   = ws + OFF_EM;
  float* part = ws + OFF_PART;
  float* out  = (float*)d_out;

  // bf16 overlays (see layout comment at top)
  unsigned short* XAh  = (unsigned short*)(ws + OFF_CTX);          // also ctxh
  unsigned short* XAl  = XAh + (size_t)NN * DD;                    // also ctxl
  unsigned short* ctxh = XAh;
  unsigned short* ctxl = XAl;
  unsigned short* Kh   = (unsigned short*)(ws + OFF_KT);
  unsigned short* Vh   = Kh + (size_t)NN * DD;
  unsigned short* Kl   = (unsigned short*)(ws + OFF_Y);
  unsigned short* Vl   = Kl + (size_t)NN * DD;
  unsigned short* xBh  = (unsigned short*)(ws + OFF_KT);           // after attn
  unsigned short* xBl  = xBh + (size_t)NN * DD;
  unsigned short* ffh  = (unsigned short*)(ws + OFF_QKV);          // after attn
  unsigned short* ffl  = ffh + (size_t)NN * DFFc;
  unsigned short* Wph  = (unsigned short*)(ws + OFF_EM);           // weight pack
  unsigned short* Wpl  = Wph + 131072;
  float* Mbuf = ws + OFF_CTX;                                      // CRF (end)

  k_embed<<<NN, DD, 0, stream>>>(sent, emb, xA, XAh, XAl);

  for (int l = 0; l < LL; l++) {
    k_packw<<<128, 256, 0, stream>>>(Wqkv + (size_t)l * 3 * DD * DD,
                                     Wo + (size_t)l * DD * DD,
                                     W1 + (size_t)l * DFFc * DD,
                                     W2 + (size_t)l * DD * DFFc, Wph, Wpl);
    // QKV: [NN,384] = XA[NN,128] . Wqkv^T, fp32 out
    k_bgemm<128, false, false><<<dim3((NN / 64) * 6), 256, 0, stream>>>(
        XAh, XAl, Wph, Wpl, bqkv + l * 3 * DD, qkv, 3 * DD, nullptr, nullptr, 6);
    k_pack<<<dim3(8, BB * HH), 256, 0, stream>>>(qkv, Kh, Kl, Vh, Vl);
    k_attn<<<dim3(2048), 256, 0, stream>>>(qkv, Kh, Kl, Vh, Vl, sent, ctxh, ctxl);
    // Wo + LN1: xB fp32 + xB pack (into dead KT region)
    k_bgemm_ln<128><<<dim3(NN / 64), 256, 0, stream>>>(
        ctxh, ctxl, Wph + 49152, Wpl + 49152, bo + l * DD, xA,
        ln1g + l * DD, ln1b + l * DD, xB, xBh, xBl, 1);
    // FF1: relu, packed-only out (into dead qkv region)
    k_bgemm<128, true, true><<<dim3((NN / 64) * 4), 256, 0, stream>>>(
        xBh, xBl, Wph + 65536, Wpl + 65536, b1f + l * DFFc, nullptr, DFFc,
        ffh, ffl, 4);
    // FF2 + LN2: xA fp32 (+ pack for next layer's QKV input)
    k_bgemm_ln<256><<<dim3(NN / 64), 256, 0, stream>>>(
        ffh, ffl, Wph + 98304, Wpl + 98304, b2f + l * DD, xB,
        ln2g + l * DD, ln2b + l * DD, xA, XAh, XAl, (l + 1 < LL) ? 1 : 0);
  }

  k_emis<<<(NN * TT + 255) / 256, 256, 0, stream>>>(xA, Wtag, btag, em);
  k_crf_scan<<<dim3(TT, 8, BB), 64, 0, stream>>>(em, sent, trans, Mbuf);
  k_crf_comb<<<BB, 64, 0, stream>>>(em, sent, tags, trans, st, et, Mbuf, part);
  k_final<<<1, 64, 0, stream>>>(part, out);
}

// Round 12
// 653.100 us; speedup vs baseline: 1.1262x; 1.1262x over previous
//
#include <hip/hip_runtime.h>
#include <hip/hip_bf16.h>

// Problem constants
#define BB   64
#define SS   512
#define DD   128
#define DFFc 256
#define HH   4
#define TT   9
#define LL   2
#define HDc  32
#define NN   (BB*SS)   // 32768 tokens

// Workspace layout (float offsets). Region time-sharing:
//  OFF_X   : xA fp32 (persistent residual)
//  OFF_Y   : xB fp32
//  OFF_QKV : qkv fp32 (until attn done) -> ffh/ffl bf16 (FF1 out, FF2 in)
//  OFF_CTX : XAh/XAl bf16 (QKV-gemm in) -> ctxh/ctxl bf16 (attn out, Wo in)
//            -> next XAh/XAl -> CRF Mbuf at the very end
//  OFF_KT  : Kh/Vh bf16 during attn -> xBh/xBl bf16 (LN1 out, FF1 in)
//  OFF_EM  : per-layer weight pack Wh|Wl (131072 floats) -> em (k_emis, end)
#define OFF_X    0
#define OFF_Y    (NN*DD)
#define OFF_QKV  (2*NN*DD)
#define OFF_CTX  (5*NN*DD)
#define OFF_KT   (6*NN*DD)
#define OFF_EM   (7*NN*DD)
#define OFF_PART (7*NN*DD + NN*TT)

typedef __attribute__((ext_vector_type(8))) short short8;
typedef __attribute__((ext_vector_type(8))) unsigned short ushort8;
typedef __attribute__((ext_vector_type(4))) float f32x4;

// Hardware RNE cvt (1 VALU; pairs fuse to v_cvt_pk_bf16_f32). Split-bf16 is
// rounding-agnostic (lo captures the remainder), so this is safe everywhere.
__device__ __forceinline__ unsigned short f2bf(float f) {
  union { __hip_bfloat16 h; unsigned short u; } cv;
  cv.h = __float2bfloat16(f);
  return cv.u;
}
__device__ __forceinline__ float bf2f(unsigned short h) {
  return __uint_as_float(((unsigned int)h) << 16);
}

// ---------------------------------------------------------------------------
// Embedding + positional encoding; emits fp32 AND bf16 hi/lo pack.
__global__ void k_embed(const int* __restrict__ sent, const float* __restrict__ emb,
                        float* __restrict__ x,
                        unsigned short* __restrict__ xh, unsigned short* __restrict__ xl) {
  int n = blockIdx.x;
  int d = threadIdx.x;
  int tok = sent[n];
  int s = n & (SS - 1);
  float e = (tok != 0) ? emb[(size_t)tok * DD + d] : 0.f;
  int i = d >> 1;
  float dv = expf((float)(2 * i) * (-9.210340371976184f / (float)DD));
  float ang = (float)s * dv;
  float pe = (d & 1) ? cosf(ang) : sinf(ang);
  float v = e + pe;
  size_t o = (size_t)n * DD + d;
  x[o] = v;
  unsigned short h = f2bf(v);
  xh[o] = h;
  xl[o] = f2bf(v - bf2f(h));
}

// ---------------------------------------------------------------------------
// Pack one layer's weights to bf16 hi/lo into the em region.
// Layout (ushort offsets): Wqkv[0,49152) Wo[49152,65536) W1[65536,98304) W2[98304,131072)
__global__ void k_packw(const float* __restrict__ Wqkv, const float* __restrict__ Wo,
                        const float* __restrict__ W1, const float* __restrict__ W2,
                        unsigned short* __restrict__ Wh, unsigned short* __restrict__ Wl) {
  int idx = (blockIdx.x * 256 + threadIdx.x) * 4;   // 131072 floats total
  const float* src;
  int off;
  if (idx < 49152)      { src = Wqkv; off = idx; }
  else if (idx < 65536) { src = Wo;   off = idx - 49152; }
  else if (idx < 98304) { src = W1;   off = idx - 65536; }
  else                  { src = W2;   off = idx - 98304; }
  float4 v = *(const float4*)(src + off);
  unsigned short h0 = f2bf(v.x), h1 = f2bf(v.y), h2 = f2bf(v.z), h3 = f2bf(v.w);
  Wh[idx + 0] = h0; Wh[idx + 1] = h1; Wh[idx + 2] = h2; Wh[idx + 3] = h3;
  Wl[idx + 0] = f2bf(v.x - bf2f(h0));
  Wl[idx + 1] = f2bf(v.y - bf2f(h1));
  Wl[idx + 2] = f2bf(v.z - bf2f(h2));
  Wl[idx + 3] = f2bf(v.w - bf2f(h3));
}

// ---------------------------------------------------------------------------
// MFMA GEMM (split-bf16 3-term): Y[n][c] = act(Xrow . Wrow + bias).
template <int KTOT, bool RELU, bool PACKOUT>
__global__ __launch_bounds__(256) void k_bgemm(
    const unsigned short* __restrict__ Xh, const unsigned short* __restrict__ Xl,
    const unsigned short* __restrict__ Wh, const unsigned short* __restrict__ Wl,
    const float* __restrict__ bias, float* __restrict__ Y, int ldY,
    unsigned short* __restrict__ Yh, unsigned short* __restrict__ Yl,
    int ncb) {
  const int id = blockIdx.x;
  const int cb = id % ncb, rb = id / ncb;
  const int tid = threadIdx.x, w = tid >> 6, lane = tid & 63;
  const int l15 = lane & 15, kg = lane >> 4;
  const int n0 = rb * 64 + w * 16;
  const int c0 = cb * 64;
  f32x4 acc[4] = {};
  const unsigned short* xph = Xh + (size_t)(n0 + l15) * KTOT + kg * 8;
  const unsigned short* xpl = Xl + (size_t)(n0 + l15) * KTOT + kg * 8;
  #pragma unroll
  for (int ks = 0; ks < KTOT / 32; ks++) {
    short8 ah = *(const short8*)(xph + ks * 32);
    short8 al = *(const short8*)(xpl + ks * 32);
    #pragma unroll
    for (int ct = 0; ct < 4; ct++) {
      size_t wo = (size_t)(c0 + ct * 16 + l15) * KTOT + ks * 32 + kg * 8;
      short8 bh = *(const short8*)(Wh + wo);
      short8 bl = *(const short8*)(Wl + wo);
      acc[ct] = __builtin_amdgcn_mfma_f32_16x16x32_bf16(ah, bh, acc[ct], 0, 0, 0);
      acc[ct] = __builtin_amdgcn_mfma_f32_16x16x32_bf16(ah, bl, acc[ct], 0, 0, 0);
      acc[ct] = __builtin_amdgcn_mfma_f32_16x16x32_bf16(al, bh, acc[ct], 0, 0, 0);
    }
  }
  // D layout: row = kg*4+j -> n, col = l15 -> c
  #pragma unroll
  for (int ct = 0; ct < 4; ct++) {
    int c = c0 + ct * 16 + l15;
    float bi = bias[c];
    #pragma unroll
    for (int j = 0; j < 4; j++) {
      float v = acc[ct][j] + bi;
      if (RELU) v = fmaxf(v, 0.f);
      int n = n0 + kg * 4 + j;
      if (PACKOUT) {
        unsigned short h = f2bf(v);
        Yh[(size_t)n * ldY + c] = h;
        Yl[(size_t)n * ldY + c] = f2bf(v - bf2f(h));
      } else {
        Y[(size_t)n * ldY + c] = v;
      }
    }
  }
}

// ---------------------------------------------------------------------------
// MFMA GEMM + bias + residual + LayerNorm (full 128-col rows per block).
template <int KTOT>
__global__ __launch_bounds__(256) void k_bgemm_ln(
    const unsigned short* __restrict__ Xh, const unsigned short* __restrict__ Xl,
    const unsigned short* __restrict__ Wh, const unsigned short* __restrict__ Wl,
    const float* __restrict__ bias, const float* __restrict__ Res,
    const float* __restrict__ gam, const float* __restrict__ bet,
    float* __restrict__ Y,
    unsigned short* __restrict__ Yh, unsigned short* __restrict__ Yl,
    int dopack) {
  const int tid = threadIdx.x, w = tid >> 6, lane = tid & 63;
  const int l15 = lane & 15, kg = lane >> 4;
  const int n0 = blockIdx.x * 64 + w * 16;
  f32x4 acc[8] = {};
  const unsigned short* xph = Xh + (size_t)(n0 + l15) * KTOT + kg * 8;
  const unsigned short* xpl = Xl + (size_t)(n0 + l15) * KTOT + kg * 8;
  #pragma unroll
  for (int ks = 0; ks < KTOT / 32; ks++) {
    short8 ah = *(const short8*)(xph + ks * 32);
    short8 al = *(const short8*)(xpl + ks * 32);
    #pragma unroll
    for (int ct = 0; ct < 8; ct++) {
      size_t wo = (size_t)(ct * 16 + l15) * KTOT + ks * 32 + kg * 8;
      short8 bh = *(const short8*)(Wh + wo);
      short8 bl = *(const short8*)(Wl + wo);
      acc[ct] = __builtin_amdgcn_mfma_f32_16x16x32_bf16(ah, bh, acc[ct], 0, 0, 0);
      acc[ct] = __builtin_amdgcn_mfma_f32_16x16x32_bf16(ah, bl, acc[ct], 0, 0, 0);
      acc[ct] = __builtin_amdgcn_mfma_f32_16x16x32_bf16(al, bh, acc[ct], 0, 0, 0);
    }
  }
  #pragma unroll
  for (int j = 0; j < 4; j++) {
    int n = n0 + kg * 4 + j;
    float v[8], s1 = 0.f, s2 = 0.f;
    #pragma unroll
    for (int ct = 0; ct < 8; ct++) {
      int c = ct * 16 + l15;
      float t = acc[ct][j] + bias[c] + Res[(size_t)n * DD + c];
      v[ct] = t;
      s1 += t;
      s2 += t * t;
    }
    #pragma unroll
    for (int off = 1; off <= 8; off <<= 1) {
      s1 += __shfl_xor(s1, off);
      s2 += __shfl_xor(s2, off);
    }
    float mu = s1 * 0.0078125f;
    float var = s2 * 0.0078125f - mu * mu;
    float rstd = rsqrtf(var + 1e-5f);
    #pragma unroll
    for (int ct = 0; ct < 8; ct++) {
      int c = ct * 16 + l15;
      float o = (v[ct] - mu) * rstd * gam[c] + bet[c];
      size_t oo = (size_t)n * DD + c;
      Y[oo] = o;
      if (dopack) {
        unsigned short h = f2bf(o);
        Yh[oo] = h;
        Yl[oo] = f2bf(o - bf2f(h));
      }
    }
  }
}

// ---------------------------------------------------------------------------
// Pack K and V of qkv into bf16 (single-term: attention tolerates bf16 —
// scores ~0.1 scale, softmax normalizes, PV errors average down ~1e-5).
// Kh [bh][s][32], Vh [bh][32][s].
__global__ void k_pack(const float* __restrict__ qkv,
                       unsigned short* __restrict__ Kh, unsigned short* __restrict__ Vh) {
  const int st = blockIdx.x * 64;
  const int bh = blockIdx.y;
  const int b = bh >> 2, h = bh & 3;
  const int tid = threadIdx.x;
  __shared__ float tile[64][33];
  #pragma unroll
  for (int p = 0; p < 8; p++) {
    int sl = p * 8 + (tid >> 5);
    int d = tid & 31;
    const float* src = qkv + (size_t)(b * SS + st + sl) * 384 + h * 32 + d;
    Kh[(size_t)(bh * SS + st + sl) * 32 + d] = f2bf(src[128]);
    tile[sl][d] = src[256];              // V slice to LDS for transpose
  }
  __syncthreads();
  int d = tid >> 3, s0 = (tid & 7) * 8;
  ushort8 vh;
  #pragma unroll
  for (int i = 0; i < 8; i++) vh[i] = f2bf(tile[s0 + i][d]);
  *(ushort8*)&Vh[(size_t)(bh * 32 + d) * SS + st + s0] = vh;
}

// ---------------------------------------------------------------------------
// MFMA attention, single-term bf16 (r10: dropped ql/Kl/Vl/Pl — error ~1e-5,
// provably below all other error sources; see r10 analysis).
__global__ __launch_bounds__(256) void k_attn(const float* __restrict__ qkv,
    const unsigned short* __restrict__ Kh, const unsigned short* __restrict__ Vh,
    const int* __restrict__ sent,
    unsigned short* __restrict__ ctxh, unsigned short* __restrict__ ctxl) {
  const int id = blockIdx.x;
  const int xcd = id & 7, rem = id >> 3;
  const int qt = rem & 7;                 // 0..7
  const int bh = xcd + 8 * (rem >> 3);    // 0..255
  const int b = bh >> 2, h = bh & 3;
  const int tid = threadIdx.x, w = tid >> 6, lane = tid & 63;
  const int l15 = lane & 15, kg = lane >> 4;

  __shared__ float kb_lds[512];
  __shared__ unsigned short Ph[4][16][136];   // [wave][q][ks(128)+pad]
  __shared__ float l_lds[4][16];

  for (int i = tid; i < 512; i += 256)
    kb_lds[i] = (sent[b * SS + i] != 0) ? 0.f : -1e9f;
  __syncthreads();

  const int qrow = qt * 64 + w * 16 + l15;
  const float* qp = qkv + (size_t)(b * SS + qrow) * 384 + h * 32 + kg * 8;
  short8 qh;
  #pragma unroll
  for (int i = 0; i < 8; i++) qh[i] = (short)f2bf(qp[i]);

  f32x4 acc0 = {0.f, 0.f, 0.f, 0.f};   // ctx^T d-tile 0 (d = kg*4+j, q = l15)
  f32x4 acc1 = {0.f, 0.f, 0.f, 0.f};   // d-tile 1
  float ls[4] = {0.f, 0.f, 0.f, 0.f};
  const float scale = 0.17677669529663687f; // 1/sqrt(32)

  const unsigned short* KhB = Kh + (size_t)bh * SS * 32;
  const unsigned short* VhB = Vh + (size_t)bh * 32 * SS;

  for (int c = 0; c < 4; c++) {
    const int ksb = c * 128;
    f32x4 sc[8];
    #pragma unroll
    for (int t = 0; t < 8; t++) {
      short8 kh_ = *(const short8*)(KhB + (size_t)(ksb + t * 16 + l15) * 32 + kg * 8);
      f32x4 z = {0.f, 0.f, 0.f, 0.f};
      sc[t] = __builtin_amdgcn_mfma_f32_16x16x32_bf16(qh, kh_, z, 0, 0, 0);
    }
    #pragma unroll
    for (int t = 0; t < 8; t++) {
      float kbv = kb_lds[ksb + t * 16 + l15];
      #pragma unroll
      for (int j = 0; j < 4; j++) {
        float s = fmaf(sc[t][j], scale, kbv);
        float p = __expf(s);               // masked: exp(~-1e9) = 0 exactly
        ls[j] += p;
        Ph[w][kg * 4 + j][t * 16 + l15] = f2bf(p);
      }
    }
    #pragma unroll
    for (int k4 = 0; k4 < 4; k4++) {
      short8 ph_ = *(const short8*)&Ph[w][l15][k4 * 32 + kg * 8];
      short8 vh0 = *(const short8*)(VhB + (size_t)l15 * SS + ksb + k4 * 32 + kg * 8);
      short8 vh1 = *(const short8*)(VhB + (size_t)(16 + l15) * SS + ksb + k4 * 32 + kg * 8);
      acc0 = __builtin_amdgcn_mfma_f32_16x16x32_bf16(vh0, ph_, acc0, 0, 0, 0);
      acc1 = __builtin_amdgcn_mfma_f32_16x16x32_bf16(vh1, ph_, acc1, 0, 0, 0);
    }
  }
  #pragma unroll
  for (int j = 0; j < 4; j++) {
    #pragma unroll
    for (int off = 1; off <= 8; off <<= 1) ls[j] += __shfl_xor(ls[j], off);
  }
  if (l15 == 0) {
    #pragma unroll
    for (int j = 0; j < 4; j++) l_lds[w][kg * 4 + j] = ls[j];
  }
  float linv = 1.f / l_lds[w][l15];
  size_t co = (size_t)(b * SS + qrow) * DD + h * 32;
  #pragma unroll
  for (int j = 0; j < 4; j++) {
    float v0 = acc0[j] * linv;
    float v1 = acc1[j] * linv;
    unsigned short h0 = f2bf(v0), h1 = f2bf(v1);
    ctxh[co + kg * 4 + j] = h0;
    ctxl[co + kg * 4 + j] = f2bf(v0 - bf2f(h0));
    ctxh[co + 16 + kg * 4 + j] = h1;
    ctxl[co + 16 + kg * 4 + j] = f2bf(v1 - bf2f(h1));
  }
}

// ---------------------------------------------------------------------------
__global__ void k_emis(const float* __restrict__ X, const float* __restrict__ Wtag,
                       const float* __restrict__ btag, float* __restrict__ em) {
  int idx = blockIdx.x * 256 + threadIdx.x;
  if (idx >= NN * TT) return;
  int n = idx / TT, t = idx - n * TT;
  const float* xr = X + (size_t)n * DD;
  const float* wr = Wtag + (size_t)t * DD;
  float acc = 0.f;
  #pragma unroll
  for (int k = 0; k < DD / 4; k++) {
    float4 x4 = *(const float4*)(xr + 4 * k);
    float4 w4 = *(const float4*)(wr + 4 * k);
    acc += x4.x * w4.x + x4.y * w4.y + x4.z * w4.z + x4.w * w4.w;
  }
  em[idx] = acc + btag[t];
}

// ---------------------------------------------------------------------------
// CRF log-semiring matrix scan (r8, verified).
__global__ void k_crf_scan(const float* __restrict__ em, const int* __restrict__ sent,
                           const float* __restrict__ trans, float* __restrict__ M) {
  const int i = blockIdx.x;     // row 0..8
  const int c = blockIdx.y;     // chunk 0..7
  const int b = blockIdx.z;     // batch
  const int lane = threadIdx.x; // 64
  const int j = (lane < TT) ? lane : 0;
  float tr[TT];
  #pragma unroll
  for (int k = 0; k < TT; k++) tr[k] = trans[k * TT + j];
  const float* emb_ = em + (size_t)b * SS * TT;
  float v = (j == i) ? 0.f : -1e30f;
  const int s0 = 1 + c * 64;
  const int s1 = (s0 + 64 < SS) ? s0 + 64 : SS;
  for (int s = s0; s < s1; s++) {
    int tok = sent[b * SS + s];
    if (tok != 0) {
      float a[TT];
      #pragma unroll
      for (int k = 0; k < TT; k++) a[k] = __shfl(v, k) + tr[k];
      float m = a[0];
      #pragma unroll
      for (int k = 1; k < TT; k++) m = fmaxf(m, a[k]);
      float sum = 0.f;
      #pragma unroll
      for (int k = 0; k < TT; k++) sum += __expf(a[k] - m);
      v = emb_[s * TT + j] + m + __logf(sum);
    }
  }
  if (lane < TT) M[(((size_t)b * 8 + c) * TT + i) * TT + j] = v;
}

__global__ void k_crf_comb(const float* __restrict__ em, const int* __restrict__ sent,
                           const int* __restrict__ tags, const float* __restrict__ trans,
                           const float* __restrict__ start_t, const float* __restrict__ end_t,
                           const float* __restrict__ M, float* __restrict__ part) {
  const int b = blockIdx.x;
  const int lane = threadIdx.x;
  const int j = (lane < TT) ? lane : 0;
  const float* emb_ = em + (size_t)b * SS * TT;
  float fv = start_t[j] + emb_[j];
  #pragma unroll
  for (int c = 0; c < 8; c++) {
    const float* Mc = M + (((size_t)b * 8 + c) * TT) * TT;
    float a[TT];
    #pragma unroll
    for (int k = 0; k < TT; k++) a[k] = __shfl(fv, k) + Mc[k * TT + j];
    float m = a[0];
    #pragma unroll
    for (int k = 1; k < TT; k++) m = fmaxf(m, a[k]);
    float sum = 0.f;
    #pragma unroll
    for (int k = 0; k < TT; k++) sum += __expf(a[k] - m);
    fv = m + __logf(sum);
  }
  float aa[TT];
  #pragma unroll
  for (int i = 0; i < TT; i++) aa[i] = __shfl(fv, i) + end_t[i];
  float m2 = aa[0];
  #pragma unroll
  for (int i = 1; i < TT; i++) m2 = fmaxf(m2, aa[i]);
  float sum2 = 0.f;
  #pragma unroll
  for (int i = 0; i < TT; i++) sum2 += __expf(aa[i] - m2);
  float fwd = m2 + __logf(sum2);
  float p = 0.f;
  int cnt = 0;
  #pragma unroll
  for (int ii = 0; ii < 8; ii++) {
    int s = lane + 64 * ii;
    cnt += (sent[b * SS + s] != 0) ? 1 : 0;
    int s2 = s + 1;
    if (s2 < SS && sent[b * SS + s2] != 0) {
      int tp = tags[b * SS + s2 - 1];
      int tc = tags[b * SS + s2];
      p += trans[tp * TT + tc] + emb_[(size_t)s2 * TT + tc];
    }
  }
  #pragma unroll
  for (int off = 32; off >= 1; off >>= 1) {
    p += __shfl_xor(p, off);
    cnt += __shfl_xor(cnt, off);
  }
  if (lane == 0) {
    int t0 = tags[b * SS];
    float score = start_t[t0] + emb_[t0] + p;
    int lastt = tags[b * SS + cnt - 1];
    score += end_t[lastt];
    part[b] = fwd - score;
  }
}

__global__ void k_final(const float* __restrict__ part, float* __restrict__ out) {
  float v = part[threadIdx.x];
  #pragma unroll
  for (int off = 32; off >= 1; off >>= 1) v += __shfl_xor(v, off);
  if (threadIdx.x == 0) out[0] = v * (1.f / 64.f);
}

// ---------------------------------------------------------------------------
extern "C" void kernel_launch(void* const* d_in, const int* in_sizes, int n_in,
                              void* d_out, int out_size, void* d_ws, size_t ws_size,
                              hipStream_t stream) {
  const int*   sent  = (const int*)d_in[0];
  const int*   tags  = (const int*)d_in[1];
  const float* emb   = (const float*)d_in[2];
  const float* Wqkv  = (const float*)d_in[3];
  const float* bqkv  = (const float*)d_in[4];
  const float* Wo    = (const float*)d_in[5];
  const float* bo    = (const float*)d_in[6];
  const float* W1    = (const float*)d_in[7];
  const float* b1f   = (const float*)d_in[8];
  const float* W2    = (const float*)d_in[9];
  const float* b2f   = (const float*)d_in[10];
  const float* ln1g  = (const float*)d_in[11];
  const float* ln1b  = (const float*)d_in[12];
  const float* ln2g  = (const float*)d_in[13];
  const float* ln2b  = (const float*)d_in[14];
  const float* Wtag  = (const float*)d_in[15];
  const float* btag  = (const float*)d_in[16];
  const float* trans = (const float*)d_in[17];
  const float* st    = (const float*)d_in[18];
  const float* et    = (const float*)d_in[19];

  float* ws   = (float*)d_ws;
  float* xA   = ws + OFF_X;
  float* xB   = ws + OFF_Y;
  float* qkv  = ws + OFF_QKV;
  float* em   = ws + OFF_EM;
  float* part = ws + OFF_PART;
  float* out  = (float*)d_out;

  // bf16 overlays (see layout comment at top)
  unsigned short* XAh  = (unsigned short*)(ws + OFF_CTX);          // also ctxh
  unsigned short* XAl  = XAh + (size_t)NN * DD;                    // also ctxl
  unsigned short* ctxh = XAh;
  unsigned short* ctxl = XAl;
  unsigned short* Kh   = (unsigned short*)(ws + OFF_KT);
  unsigned short* Vh   = Kh + (size_t)NN * DD;
  unsigned short* xBh  = (unsigned short*)(ws + OFF_KT);           // after attn
  unsigned short* xBl  = xBh + (size_t)NN * DD;
  unsigned short* ffh  = (unsigned short*)(ws + OFF_QKV);          // after attn
  unsigned short* ffl  = ffh + (size_t)NN * DFFc;
  unsigned short* Wph  = (unsigned short*)(ws + OFF_EM);           // weight pack
  unsigned short* Wpl  = Wph + 131072;
  float* Mbuf = ws + OFF_CTX;                                      // CRF (end)

  k_embed<<<NN, DD, 0, stream>>>(sent, emb, xA, XAh, XAl);

  for (int l = 0; l < LL; l++) {
    k_packw<<<128, 256, 0, stream>>>(Wqkv + (size_t)l * 3 * DD * DD,
                                     Wo + (size_t)l * DD * DD,
                                     W1 + (size_t)l * DFFc * DD,
                                     W2 + (size_t)l * DD * DFFc, Wph, Wpl);
    // QKV: [NN,384] = XA[NN,128] . Wqkv^T, fp32 out
    k_bgemm<128, false, false><<<dim3((NN / 64) * 6), 256, 0, stream>>>(
        XAh, XAl, Wph, Wpl, bqkv + l * 3 * DD, qkv, 3 * DD, nullptr, nullptr, 6);
    k_pack<<<dim3(8, BB * HH), 256, 0, stream>>>(qkv, Kh, Vh);
    k_attn<<<dim3(2048), 256, 0, stream>>>(qkv, Kh, Vh, sent, ctxh, ctxl);
    // Wo + LN1: xB fp32 + xB pack (into dead KT region)
    k_bgemm_ln<128><<<dim3(NN / 64), 256, 0, stream>>>(
        ctxh, ctxl, Wph + 49152, Wpl + 49152, bo + l * DD, xA,
        ln1g + l * DD, ln1b + l * DD, xB, xBh, xBl, 1);
    // FF1: relu, packed-only out (into dead qkv region)
    k_bgemm<128, true, true><<<dim3((NN / 64) * 4), 256, 0, stream>>>(
        xBh, xBl, Wph + 65536, Wpl + 65536, b1f + l * DFFc, nullptr, DFFc,
        ffh, ffl, 4);
    // FF2 + LN2: xA fp32 (+ pack for next layer's QKV input)
    k_bgemm_ln<256><<<dim3(NN / 64), 256, 0, stream>>>(
        ffh, ffl, Wph + 98304, Wpl + 98304, b2f + l * DD, xB,
        ln2g + l * DD, ln2b + l * DD, xA, XAh, XAl, (l + 1 < LL) ? 1 : 0);
  }

  k_emis<<<(NN * TT + 255) / 256, 256, 0, stream>>>(xA, Wtag, btag, em);
  k_crf_scan<<<dim3(TT, 8, BB), 64, 0, stream>>>(em, sent, trans, Mbuf);
  k_crf_comb<<<BB, 64, 0, stream>>>(em, sent, tags, trans, st, et, Mbuf, part);
  k_final<<<1, 64, 0, stream>>>(part, out);
}

// Round 13
// 643.927 us; speedup vs baseline: 1.1423x; 1.0142x over previous
//
#include <hip/hip_runtime.h>
#include <hip/hip_bf16.h>

// Problem constants
#define BB   64
#define SS   512
#define DD   128
#define DFFc 256
#define HH   4
#define TT   9
#define LL   2
#define HDc  32
#define NN   (BB*SS)   // 32768 tokens

// Workspace layout (float offsets). Region time-sharing:
//  OFF_X   : xA fp32 (persistent residual)
//  OFF_Y   : xB fp32
//  OFF_QKV : ffh/ffl bf16 [2*NN*DD floats); Qh bf16 at +4*NN*DD/... (disjoint)
//  OFF_CTX : XAh/XAl bf16 (QKV-gemm in) -> ctxh/ctxl bf16 (attn out, Wo in)
//            -> next XAh/XAl -> CRF Mbuf at the very end
//  OFF_KT  : Kh/Vh bf16 during attn -> xBh/xBl bf16 (LN1 out, FF1 in)
//  OFF_EM  : per-layer weight pack Wh|Wl (131072 floats) -> em (k_emis, end)
#define OFF_X    0
#define OFF_Y    (NN*DD)
#define OFF_QKV  (2*NN*DD)
#define OFF_CTX  (5*NN*DD)
#define OFF_KT   (6*NN*DD)
#define OFF_EM   (7*NN*DD)
#define OFF_PART (7*NN*DD + NN*TT)

typedef __attribute__((ext_vector_type(8))) short short8;
typedef __attribute__((ext_vector_type(8))) unsigned short ushort8;
typedef __attribute__((ext_vector_type(4))) float f32x4;

// Hardware RNE cvt (1 VALU; pairs fuse to v_cvt_pk_bf16_f32).
__device__ __forceinline__ unsigned short f2bf(float f) {
  union { __hip_bfloat16 h; unsigned short u; } cv;
  cv.h = __float2bfloat16(f);
  return cv.u;
}
__device__ __forceinline__ float bf2f(unsigned short h) {
  return __uint_as_float(((unsigned int)h) << 16);
}

// ---------------------------------------------------------------------------
// Embedding + positional encoding; emits fp32 AND bf16 hi/lo pack.
__global__ void k_embed(const int* __restrict__ sent, const float* __restrict__ emb,
                        float* __restrict__ x,
                        unsigned short* __restrict__ xh, unsigned short* __restrict__ xl) {
  int n = blockIdx.x;
  int d = threadIdx.x;
  int tok = sent[n];
  int s = n & (SS - 1);
  float e = (tok != 0) ? emb[(size_t)tok * DD + d] : 0.f;
  int i = d >> 1;
  float dv = expf((float)(2 * i) * (-9.210340371976184f / (float)DD));
  float ang = (float)s * dv;
  float pe = (d & 1) ? cosf(ang) : sinf(ang);
  float v = e + pe;
  size_t o = (size_t)n * DD + d;
  x[o] = v;
  unsigned short h = f2bf(v);
  xh[o] = h;
  xl[o] = f2bf(v - bf2f(h));
}

// ---------------------------------------------------------------------------
// Pack one layer's weights to bf16 hi/lo into the em region.
// Layout (ushort offsets): Wqkv[0,49152) Wo[49152,65536) W1[65536,98304) W2[98304,131072)
__global__ void k_packw(const float* __restrict__ Wqkv, const float* __restrict__ Wo,
                        const float* __restrict__ W1, const float* __restrict__ W2,
                        unsigned short* __restrict__ Wh, unsigned short* __restrict__ Wl) {
  int idx = (blockIdx.x * 256 + threadIdx.x) * 4;   // 131072 floats total
  const float* src;
  int off;
  if (idx < 49152)      { src = Wqkv; off = idx; }
  else if (idx < 65536) { src = Wo;   off = idx - 49152; }
  else if (idx < 98304) { src = W1;   off = idx - 65536; }
  else                  { src = W2;   off = idx - 98304; }
  float4 v = *(const float4*)(src + off);
  unsigned short h0 = f2bf(v.x), h1 = f2bf(v.y), h2 = f2bf(v.z), h3 = f2bf(v.w);
  Wh[idx + 0] = h0; Wh[idx + 1] = h1; Wh[idx + 2] = h2; Wh[idx + 3] = h3;
  Wl[idx + 0] = f2bf(v.x - bf2f(h0));
  Wl[idx + 1] = f2bf(v.y - bf2f(h1));
  Wl[idx + 2] = f2bf(v.z - bf2f(h2));
  Wl[idx + 3] = f2bf(v.w - bf2f(h3));
}

// ---------------------------------------------------------------------------
// QKV GEMM (split-bf16 3-term) with FUSED bf16 pack epilogue (r13):
// writes Q/K/V directly in the attention-consumer layouts — no fp32 qkv,
// no k_pack. XCD swizzle: the 6 col-blocks of one row-block share an XCD.
__global__ __launch_bounds__(256) void k_bgemm_qkv(
    const unsigned short* __restrict__ Xh, const unsigned short* __restrict__ Xl,
    const unsigned short* __restrict__ Wh, const unsigned short* __restrict__ Wl,
    const float* __restrict__ bias,
    unsigned short* __restrict__ Qh, unsigned short* __restrict__ Kh,
    unsigned short* __restrict__ Vh) {
  const int id = blockIdx.x;                 // 3072 blocks
  const int xcd = id & 7;
  const int idx = id >> 3;
  const int cb = idx % 6;
  const int rb = (idx / 6) * 8 + xcd;        // 0..511, bijective
  const int tid = threadIdx.x, w = tid >> 6, lane = tid & 63;
  const int l15 = lane & 15, kg = lane >> 4;
  const int n0 = rb * 64 + w * 16;
  const int c0 = cb * 64;
  f32x4 acc[4] = {};
  const unsigned short* xph = Xh + (size_t)(n0 + l15) * DD + kg * 8;
  const unsigned short* xpl = Xl + (size_t)(n0 + l15) * DD + kg * 8;
  #pragma unroll
  for (int ks = 0; ks < 4; ks++) {
    short8 ah = *(const short8*)(xph + ks * 32);
    short8 al = *(const short8*)(xpl + ks * 32);
    #pragma unroll
    for (int ct = 0; ct < 4; ct++) {
      size_t wo = (size_t)(c0 + ct * 16 + l15) * DD + ks * 32 + kg * 8;
      short8 bh = *(const short8*)(Wh + wo);
      short8 bl = *(const short8*)(Wl + wo);
      acc[ct] = __builtin_amdgcn_mfma_f32_16x16x32_bf16(ah, bh, acc[ct], 0, 0, 0);
      acc[ct] = __builtin_amdgcn_mfma_f32_16x16x32_bf16(ah, bl, acc[ct], 0, 0, 0);
      acc[ct] = __builtin_amdgcn_mfma_f32_16x16x32_bf16(al, bh, acc[ct], 0, 0, 0);
    }
  }
  // D layout: row = kg*4+j -> n, col = l15 -> c
  #pragma unroll
  for (int ct = 0; ct < 4; ct++) {
    int c = c0 + ct * 16 + l15;
    float bi = bias[c];
    #pragma unroll
    for (int j = 0; j < 4; j++) {
      float v = acc[ct][j] + bi;
      int n = n0 + kg * 4 + j;
      unsigned short hv = f2bf(v);
      if (cb < 2) {                       // Q: [n][c], c in [0,128)
        Qh[(size_t)n * DD + c] = hv;
      } else if (cb < 4) {                // K: [bh][s][32]
        int cc = c - 128, h = cc >> 5, d = cc & 31;
        int b = n >> 9, s = n & 511;
        Kh[((size_t)(b * 4 + h) * SS + s) * 32 + d] = hv;
      } else {                            // V (transposed): [bh][32][s]
        int cc = c - 256, h = cc >> 5, d = cc & 31;
        int b = n >> 9, s = n & 511;
        Vh[((size_t)(b * 4 + h) * 32 + d) * SS + s] = hv;
      }
    }
  }
}

// ---------------------------------------------------------------------------
// MFMA GEMM (split-bf16 3-term): Y[n][c] = act(Xrow . Wrow + bias).
// XCD swizzle: ncb col-blocks of a row-block share an XCD (r13).
template <int KTOT, bool RELU, bool PACKOUT>
__global__ __launch_bounds__(256) void k_bgemm(
    const unsigned short* __restrict__ Xh, const unsigned short* __restrict__ Xl,
    const unsigned short* __restrict__ Wh, const unsigned short* __restrict__ Wl,
    const float* __restrict__ bias, float* __restrict__ Y, int ldY,
    unsigned short* __restrict__ Yh, unsigned short* __restrict__ Yl,
    int ncb) {
  const int id = blockIdx.x;
  const int xcd = id & 7;
  const int idx = id >> 3;
  const int cb = idx % ncb;
  const int rb = (idx / ncb) * 8 + xcd;
  const int tid = threadIdx.x, w = tid >> 6, lane = tid & 63;
  const int l15 = lane & 15, kg = lane >> 4;
  const int n0 = rb * 64 + w * 16;
  const int c0 = cb * 64;
  f32x4 acc[4] = {};
  const unsigned short* xph = Xh + (size_t)(n0 + l15) * KTOT + kg * 8;
  const unsigned short* xpl = Xl + (size_t)(n0 + l15) * KTOT + kg * 8;
  #pragma unroll
  for (int ks = 0; ks < KTOT / 32; ks++) {
    short8 ah = *(const short8*)(xph + ks * 32);
    short8 al = *(const short8*)(xpl + ks * 32);
    #pragma unroll
    for (int ct = 0; ct < 4; ct++) {
      size_t wo = (size_t)(c0 + ct * 16 + l15) * KTOT + ks * 32 + kg * 8;
      short8 bh = *(const short8*)(Wh + wo);
      short8 bl = *(const short8*)(Wl + wo);
      acc[ct] = __builtin_amdgcn_mfma_f32_16x16x32_bf16(ah, bh, acc[ct], 0, 0, 0);
      acc[ct] = __builtin_amdgcn_mfma_f32_16x16x32_bf16(ah, bl, acc[ct], 0, 0, 0);
      acc[ct] = __builtin_amdgcn_mfma_f32_16x16x32_bf16(al, bh, acc[ct], 0, 0, 0);
    }
  }
  #pragma unroll
  for (int ct = 0; ct < 4; ct++) {
    int c = c0 + ct * 16 + l15;
    float bi = bias[c];
    #pragma unroll
    for (int j = 0; j < 4; j++) {
      float v = acc[ct][j] + bi;
      if (RELU) v = fmaxf(v, 0.f);
      int n = n0 + kg * 4 + j;
      if (PACKOUT) {
        unsigned short h = f2bf(v);
        Yh[(size_t)n * ldY + c] = h;
        Yl[(size_t)n * ldY + c] = f2bf(v - bf2f(h));
      } else {
        Y[(size_t)n * ldY + c] = v;
      }
    }
  }
}

// ---------------------------------------------------------------------------
// MFMA GEMM + bias + residual + LayerNorm (full 128-col rows per block).
template <int KTOT>
__global__ __launch_bounds__(256) void k_bgemm_ln(
    const unsigned short* __restrict__ Xh, const unsigned short* __restrict__ Xl,
    const unsigned short* __restrict__ Wh, const unsigned short* __restrict__ Wl,
    const float* __restrict__ bias, const float* __restrict__ Res,
    const float* __restrict__ gam, const float* __restrict__ bet,
    float* __restrict__ Y,
    unsigned short* __restrict__ Yh, unsigned short* __restrict__ Yl,
    int dopack) {
  const int tid = threadIdx.x, w = tid >> 6, lane = tid & 63;
  const int l15 = lane & 15, kg = lane >> 4;
  const int n0 = blockIdx.x * 64 + w * 16;
  f32x4 acc[8] = {};
  const unsigned short* xph = Xh + (size_t)(n0 + l15) * KTOT + kg * 8;
  const unsigned short* xpl = Xl + (size_t)(n0 + l15) * KTOT + kg * 8;
  #pragma unroll
  for (int ks = 0; ks < KTOT / 32; ks++) {
    short8 ah = *(const short8*)(xph + ks * 32);
    short8 al = *(const short8*)(xpl + ks * 32);
    #pragma unroll
    for (int ct = 0; ct < 8; ct++) {
      size_t wo = (size_t)(ct * 16 + l15) * KTOT + ks * 32 + kg * 8;
      short8 bh = *(const short8*)(Wh + wo);
      short8 bl = *(const short8*)(Wl + wo);
      acc[ct] = __builtin_amdgcn_mfma_f32_16x16x32_bf16(ah, bh, acc[ct], 0, 0, 0);
      acc[ct] = __builtin_amdgcn_mfma_f32_16x16x32_bf16(ah, bl, acc[ct], 0, 0, 0);
      acc[ct] = __builtin_amdgcn_mfma_f32_16x16x32_bf16(al, bh, acc[ct], 0, 0, 0);
    }
  }
  #pragma unroll
  for (int j = 0; j < 4; j++) {
    int n = n0 + kg * 4 + j;
    float v[8], s1 = 0.f, s2 = 0.f;
    #pragma unroll
    for (int ct = 0; ct < 8; ct++) {
      int c = ct * 16 + l15;
      float t = acc[ct][j] + bias[c] + Res[(size_t)n * DD + c];
      v[ct] = t;
      s1 += t;
      s2 += t * t;
    }
    #pragma unroll
    for (int off = 1; off <= 8; off <<= 1) {
      s1 += __shfl_xor(s1, off);
      s2 += __shfl_xor(s2, off);
    }
    float mu = s1 * 0.0078125f;
    float var = s2 * 0.0078125f - mu * mu;
    float rstd = rsqrtf(var + 1e-5f);
    #pragma unroll
    for (int ct = 0; ct < 8; ct++) {
      int c = ct * 16 + l15;
      float o = (v[ct] - mu) * rstd * gam[c] + bet[c];
      size_t oo = (size_t)n * DD + c;
      Y[oo] = o;
      if (dopack) {
        unsigned short h = f2bf(o);
        Yh[oo] = h;
        Yl[oo] = f2bf(o - bf2f(h));
      }
    }
  }
}

// ---------------------------------------------------------------------------
// MFMA attention, single-term bf16 (r12, verified absmax 0.0). Q now read
// directly from the QKV-gemm's bf16 Qh (identical values to prior f2bf-in-attn).
__global__ __launch_bounds__(256) void k_attn(
    const unsigned short* __restrict__ Qh,
    const unsigned short* __restrict__ Kh, const unsigned short* __restrict__ Vh,
    const int* __restrict__ sent,
    unsigned short* __restrict__ ctxh, unsigned short* __restrict__ ctxl) {
  const int id = blockIdx.x;
  const int xcd = id & 7, rem = id >> 3;
  const int qt = rem & 7;                 // 0..7
  const int bh = xcd + 8 * (rem >> 3);    // 0..255
  const int b = bh >> 2, h = bh & 3;
  const int tid = threadIdx.x, w = tid >> 6, lane = tid & 63;
  const int l15 = lane & 15, kg = lane >> 4;

  __shared__ float kb_lds[512];
  __shared__ unsigned short Ph[4][16][136];   // [wave][q][ks(128)+pad]
  __shared__ float l_lds[4][16];

  for (int i = tid; i < 512; i += 256)
    kb_lds[i] = (sent[b * SS + i] != 0) ? 0.f : -1e9f;
  __syncthreads();

  const int qrow = qt * 64 + w * 16 + l15;
  short8 qh = *(const short8*)(Qh + (size_t)(b * SS + qrow) * DD + h * 32 + kg * 8);

  f32x4 acc0 = {0.f, 0.f, 0.f, 0.f};   // ctx^T d-tile 0 (d = kg*4+j, q = l15)
  f32x4 acc1 = {0.f, 0.f, 0.f, 0.f};   // d-tile 1
  float ls[4] = {0.f, 0.f, 0.f, 0.f};
  const float scale = 0.17677669529663687f; // 1/sqrt(32)

  const unsigned short* KhB = Kh + (size_t)bh * SS * 32;
  const unsigned short* VhB = Vh + (size_t)bh * 32 * SS;

  for (int c = 0; c < 4; c++) {
    const int ksb = c * 128;
    f32x4 sc[8];
    #pragma unroll
    for (int t = 0; t < 8; t++) {
      short8 kh_ = *(const short8*)(KhB + (size_t)(ksb + t * 16 + l15) * 32 + kg * 8);
      f32x4 z = {0.f, 0.f, 0.f, 0.f};
      sc[t] = __builtin_amdgcn_mfma_f32_16x16x32_bf16(qh, kh_, z, 0, 0, 0);
    }
    #pragma unroll
    for (int t = 0; t < 8; t++) {
      float kbv = kb_lds[ksb + t * 16 + l15];
      #pragma unroll
      for (int j = 0; j < 4; j++) {
        float s = fmaf(sc[t][j], scale, kbv);
        float p = __expf(s);               // masked: exp(~-1e9) = 0 exactly
        ls[j] += p;
        Ph[w][kg * 4 + j][t * 16 + l15] = f2bf(p);
      }
    }
    #pragma unroll
    for (int k4 = 0; k4 < 4; k4++) {
      short8 ph_ = *(const short8*)&Ph[w][l15][k4 * 32 + kg * 8];
      short8 vh0 = *(const short8*)(VhB + (size_t)l15 * SS + ksb + k4 * 32 + kg * 8);
      short8 vh1 = *(const short8*)(VhB + (size_t)(16 + l15) * SS + ksb + k4 * 32 + kg * 8);
      acc0 = __builtin_amdgcn_mfma_f32_16x16x32_bf16(vh0, ph_, acc0, 0, 0, 0);
      acc1 = __builtin_amdgcn_mfma_f32_16x16x32_bf16(vh1, ph_, acc1, 0, 0, 0);
    }
  }
  #pragma unroll
  for (int j = 0; j < 4; j++) {
    #pragma unroll
    for (int off = 1; off <= 8; off <<= 1) ls[j] += __shfl_xor(ls[j], off);
  }
  if (l15 == 0) {
    #pragma unroll
    for (int j = 0; j < 4; j++) l_lds[w][kg * 4 + j] = ls[j];
  }
  float linv = 1.f / l_lds[w][l15];
  size_t co = (size_t)(b * SS + qrow) * DD + h * 32;
  #pragma unroll
  for (int j = 0; j < 4; j++) {
    float v0 = acc0[j] * linv;
    float v1 = acc1[j] * linv;
    unsigned short h0 = f2bf(v0), h1 = f2bf(v1);
    ctxh[co + kg * 4 + j] = h0;
    ctxl[co + kg * 4 + j] = f2bf(v0 - bf2f(h0));
    ctxh[co + 16 + kg * 4 + j] = h1;
    ctxl[co + 16 + kg * 4 + j] = f2bf(v1 - bf2f(h1));
  }
}

// ---------------------------------------------------------------------------
__global__ void k_emis(const float* __restrict__ X, const float* __restrict__ Wtag,
                       const float* __restrict__ btag, float* __restrict__ em) {
  int idx = blockIdx.x * 256 + threadIdx.x;
  if (idx >= NN * TT) return;
  int n = idx / TT, t = idx - n * TT;
  const float* xr = X + (size_t)n * DD;
  const float* wr = Wtag + (size_t)t * DD;
  float acc = 0.f;
  #pragma unroll
  for (int k = 0; k < DD / 4; k++) {
    float4 x4 = *(const float4*)(xr + 4 * k);
    float4 w4 = *(const float4*)(wr + 4 * k);
    acc += x4.x * w4.x + x4.y * w4.y + x4.z * w4.z + x4.w * w4.w;
  }
  em[idx] = acc + btag[t];
}

// ---------------------------------------------------------------------------
// CRF log-semiring matrix scan (r8, verified).
__global__ void k_crf_scan(const float* __restrict__ em, const int* __restrict__ sent,
                           const float* __restrict__ trans, float* __restrict__ M) {
  const int i = blockIdx.x;     // row 0..8
  const int c = blockIdx.y;     // chunk 0..7
  const int b = blockIdx.z;     // batch
  const int lane = threadIdx.x; // 64
  const int j = (lane < TT) ? lane : 0;
  float tr[TT];
  #pragma unroll
  for (int k = 0; k < TT; k++) tr[k] = trans[k * TT + j];
  const float* emb_ = em + (size_t)b * SS * TT;
  float v = (j == i) ? 0.f : -1e30f;
  const int s0 = 1 + c * 64;
  const int s1 = (s0 + 64 < SS) ? s0 + 64 : SS;
  for (int s = s0; s < s1; s++) {
    int tok = sent[b * SS + s];
    if (tok != 0) {
      float a[TT];
      #pragma unroll
      for (int k = 0; k < TT; k++) a[k] = __shfl(v, k) + tr[k];
      float m = a[0];
      #pragma unroll
      for (int k = 1; k < TT; k++) m = fmaxf(m, a[k]);
      float sum = 0.f;
      #pragma unroll
      for (int k = 0; k < TT; k++) sum += __expf(a[k] - m);
      v = emb_[s * TT + j] + m + __logf(sum);
    }
  }
  if (lane < TT) M[(((size_t)b * 8 + c) * TT + i) * TT + j] = v;
}

__global__ void k_crf_comb(const float* __restrict__ em, const int* __restrict__ sent,
                           const int* __restrict__ tags, const float* __restrict__ trans,
                           const float* __restrict__ start_t, const float* __restrict__ end_t,
                           const float* __restrict__ M, float* __restrict__ part) {
  const int b = blockIdx.x;
  const int lane = threadIdx.x;
  const int j = (lane < TT) ? lane : 0;
  const float* emb_ = em + (size_t)b * SS * TT;
  float fv = start_t[j] + emb_[j];
  #pragma unroll
  for (int c = 0; c < 8; c++) {
    const float* Mc = M + (((size_t)b * 8 + c) * TT) * TT;
    float a[TT];
    #pragma unroll
    for (int k = 0; k < TT; k++) a[k] = __shfl(fv, k) + Mc[k * TT + j];
    float m = a[0];
    #pragma unroll
    for (int k = 1; k < TT; k++) m = fmaxf(m, a[k]);
    float sum = 0.f;
    #pragma unroll
    for (int k = 0; k < TT; k++) sum += __expf(a[k] - m);
    fv = m + __logf(sum);
  }
  float aa[TT];
  #pragma unroll
  for (int i = 0; i < TT; i++) aa[i] = __shfl(fv, i) + end_t[i];
  float m2 = aa[0];
  #pragma unroll
  for (int i = 1; i < TT; i++) m2 = fmaxf(m2, aa[i]);
  float sum2 = 0.f;
  #pragma unroll
  for (int i = 0; i < TT; i++) sum2 += __expf(aa[i] - m2);
  float fwd = m2 + __logf(sum2);
  float p = 0.f;
  int cnt = 0;
  #pragma unroll
  for (int ii = 0; ii < 8; ii++) {
    int s = lane + 64 * ii;
    cnt += (sent[b * SS + s] != 0) ? 1 : 0;
    int s2 = s + 1;
    if (s2 < SS && sent[b * SS + s2] != 0) {
      int tp = tags[b * SS + s2 - 1];
      int tc = tags[b * SS + s2];
      p += trans[tp * TT + tc] + emb_[(size_t)s2 * TT + tc];
    }
  }
  #pragma unroll
  for (int off = 32; off >= 1; off >>= 1) {
    p += __shfl_xor(p, off);
    cnt += __shfl_xor(cnt, off);
  }
  if (lane == 0) {
    int t0 = tags[b * SS];
    float score = start_t[t0] + emb_[t0] + p;
    int lastt = tags[b * SS + cnt - 1];
    score += end_t[lastt];
    part[b] = fwd - score;
  }
}

__global__ void k_final(const float* __restrict__ part, float* __restrict__ out) {
  float v = part[threadIdx.x];
  #pragma unroll
  for (int off = 32; off >= 1; off >>= 1) v += __shfl_xor(v, off);
  if (threadIdx.x == 0) out[0] = v * (1.f / 64.f);
}

// ---------------------------------------------------------------------------
extern "C" void kernel_launch(void* const* d_in, const int* in_sizes, int n_in,
                              void* d_out, int out_size, void* d_ws, size_t ws_size,
                              hipStream_t stream) {
  const int*   sent  = (const int*)d_in[0];
  const int*   tags  = (const int*)d_in[1];
  const float* emb   = (const float*)d_in[2];
  const float* Wqkv  = (const float*)d_in[3];
  const float* bqkv  = (const float*)d_in[4];
  const float* Wo    = (const float*)d_in[5];
  const float* bo    = (const float*)d_in[6];
  const float* W1    = (const float*)d_in[7];
  const float* b1f   = (const float*)d_in[8];
  const float* W2    = (const float*)d_in[9];
  const float* b2f   = (const float*)d_in[10];
  const float* ln1g  = (const float*)d_in[11];
  const float* ln1b  = (const float*)d_in[12];
  const float* ln2g  = (const float*)d_in[13];
  const float* ln2b  = (const float*)d_in[14];
  const float* Wtag  = (const float*)d_in[15];
  const float* btag  = (const float*)d_in[16];
  const float* trans = (const float*)d_in[17];
  const float* st    = (const float*)d_in[18];
  const float* et    = (const float*)d_in[19];

  float* ws   = (float*)d_ws;
  float* xA   = ws + OFF_X;
  float* xB   = ws + OFF_Y;
  float* em   = ws + OFF_EM;
  float* part = ws + OFF_PART;
  float* out  = (float*)d_out;

  // bf16 overlays (see layout comment at top)
  unsigned short* XAh  = (unsigned short*)(ws + OFF_CTX);          // also ctxh
  unsigned short* XAl  = XAh + (size_t)NN * DD;                    // also ctxl
  unsigned short* ctxh = XAh;
  unsigned short* ctxl = XAl;
  unsigned short* Kh   = (unsigned short*)(ws + OFF_KT);
  unsigned short* Vh   = Kh + (size_t)NN * DD;
  unsigned short* xBh  = (unsigned short*)(ws + OFF_KT);           // after attn
  unsigned short* xBl  = xBh + (size_t)NN * DD;
  unsigned short* ffh  = (unsigned short*)(ws + OFF_QKV);          // FF region (32 MB)
  unsigned short* ffl  = ffh + (size_t)NN * DFFc;
  unsigned short* Qh   = (unsigned short*)(ws + OFF_QKV + 4 * (size_t)NN * DD / 2 * 2);
  // ^ Qh at float offset OFF_QKV + 2*NN*DD... compute plainly below instead:
  Qh = (unsigned short*)(ws + (4 * (size_t)NN * DD));              // [4NN*DD,4.5NN*DD) floats
  unsigned short* Wph  = (unsigned short*)(ws + OFF_EM);           // weight pack
  unsigned short* Wpl  = Wph + 131072;
  float* Mbuf = ws + OFF_CTX;                                      // CRF (end)

  k_embed<<<NN, DD, 0, stream>>>(sent, emb, xA, XAh, XAl);

  for (int l = 0; l < LL; l++) {
    k_packw<<<128, 256, 0, stream>>>(Wqkv + (size_t)l * 3 * DD * DD,
                                     Wo + (size_t)l * DD * DD,
                                     W1 + (size_t)l * DFFc * DD,
                                     W2 + (size_t)l * DD * DFFc, Wph, Wpl);
    // QKV with fused Q/K/V bf16 pack (no fp32 qkv, no k_pack)
    k_bgemm_qkv<<<dim3((NN / 64) * 6), 256, 0, stream>>>(
        XAh, XAl, Wph, Wpl, bqkv + l * 3 * DD, Qh, Kh, Vh);
    k_attn<<<dim3(2048), 256, 0, stream>>>(Qh, Kh, Vh, sent, ctxh, ctxl);
    // Wo + LN1: xB fp32 + xB pack (into dead KT region)
    k_bgemm_ln<128><<<dim3(NN / 64), 256, 0, stream>>>(
        ctxh, ctxl, Wph + 49152, Wpl + 49152, bo + l * DD, xA,
        ln1g + l * DD, ln1b + l * DD, xB, xBh, xBl, 1);
    // FF1: relu, packed-only out (into ff region)
    k_bgemm<128, true, true><<<dim3((NN / 64) * 4), 256, 0, stream>>>(
        xBh, xBl, Wph + 65536, Wpl + 65536, b1f + l * DFFc, nullptr, DFFc,
        ffh, ffl, 4);
    // FF2 + LN2: xA fp32 (+ pack for next layer's QKV input)
    k_bgemm_ln<256><<<dim3(NN / 64), 256, 0, stream>>>(
        ffh, ffl, Wph + 98304, Wpl + 98304, b2f + l * DD, xB,
        ln2g + l * DD, ln2b + l * DD, xA, XAh, XAl, (l + 1 < LL) ? 1 : 0);
  }

  k_emis<<<(NN * TT + 255) / 256, 256, 0, stream>>>(xA, Wtag, btag, em);
  k_crf_scan<<<dim3(TT, 8, BB), 64, 0, stream>>>(em, sent, trans, Mbuf);
  k_crf_comb<<<BB, 64, 0, stream>>>(em, sent, tags, trans, st, et, Mbuf, part);
  k_final<<<1, 64, 0, stream>>>(part, out);
}